// Round 5
// baseline (719.783 us; speedup 1.0000x reference)
//
#include <hip/hip_runtime.h>

#define N_PTS   2000000
#define DIM     128
#define KSEL    15
#define TPB     256
#define NBLK    2048
#define NGRP    (NBLK * (TPB / 16))        // 32768 groups, sweep stride
#define NCAND   (NBLK * KSEL)              // 30720
#define FBIG    3.4028235e38f
#define IBIG    0x7fffffff

// ---------------------------------------------------------------------------
// Kernel 1: fused distances + per-block exact top-15.
// 16 lanes per row (2x float4/lane, coalesced). Grid-stride SWEEP: at any
// instant all 32768 groups read one contiguous ~16MB window (DRAM locality).
// Each lane keeps a guarded sorted top-15 of (d2,row) — insert is rare, the
// common path is one compare. Block epilogue: 16 group leaders dump lists to
// LDS, wave 0 does an exact 15-of-240 extraction merge, writes 15 pairs.
// Ordering is (d2, idx) lexicographic -> matches lax.top_k tie-breaking.
// ---------------------------------------------------------------------------
__global__ __launch_bounds__(TPB) void k_dist(const float* __restrict__ x,
                                              const float* __restrict__ td,
                                              float2* __restrict__ bcand) {
  const int tid = threadIdx.x;
  const int g   = tid & 15;
  const int grp = blockIdx.x * (TPB / 16) + (tid >> 4);

  const float4* x4 = (const float4*)x;
  float4 xa = x4[g];
  float4 xb = x4[g + 16];
  float xsq = xa.x*xa.x + xa.y*xa.y + xa.z*xa.z + xa.w*xa.w
            + xb.x*xb.x + xb.y*xb.y + xb.z*xb.z + xb.w*xb.w;
#pragma unroll
  for (int m = 1; m < 16; m <<= 1) xsq += __shfl_xor(xsq, m);

  const float4 x2a = make_float4(2.f*xa.x, 2.f*xa.y, 2.f*xa.z, 2.f*xa.w);
  const float4 x2b = make_float4(2.f*xb.x, 2.f*xb.y, 2.f*xb.z, 2.f*xb.w);

  float lv[KSEL]; int li[KSEL];
#pragma unroll
  for (int k = 0; k < KSEL; k++) { lv[k] = FBIG; li[k] = IBIG; }

#pragma unroll 2
  for (int row = grp; row < N_PTS; row += NGRP) {
    const float4* rp = (const float4*)(td + (size_t)row * DIM);
    float4 ta = rp[g];
    float4 tb = rp[g + 16];
    float v;
    v  = ta.x * (ta.x - x2a.x);
    v += ta.y * (ta.y - x2a.y);
    v += ta.z * (ta.z - x2a.z);
    v += ta.w * (ta.w - x2a.w);
    v += tb.x * (tb.x - x2b.x);
    v += tb.y * (tb.y - x2b.y);
    v += tb.z * (tb.z - x2b.z);
    v += tb.w * (tb.w - x2b.w);
#pragma unroll
    for (int m = 1; m < 16; m <<= 1) v += __shfl_xor(v, m);   // group reduce
    float d2 = fmaxf(v + xsq, 0.f);

    // guarded top-15 insert (rare); all static indices
    if (d2 < lv[KSEL - 1] || (d2 == lv[KSEL - 1] && row < li[KSEL - 1])) {
      float cv = d2; int ci = row;
#pragma unroll
      for (int q = 0; q < KSEL; q++) {
        bool less = (cv < lv[q]) || (cv == lv[q] && ci < li[q]);
        float nv = less ? cv : lv[q];  int ni = less ? ci : li[q];
        float xv = less ? lv[q] : cv;  int xi = less ? li[q] : ci;
        lv[q] = nv; li[q] = ni; cv = xv; ci = xi;
      }
    }
  }

  // ---- block epilogue: merge 16 leader lists (240 pairs) to exact top-15
  __shared__ float2 sml[16 * KSEL];
  if (g == 0) {
#pragma unroll
    for (int k = 0; k < KSEL; k++)
      sml[(tid >> 4) * KSEL + k] = make_float2(lv[k], __int_as_float(li[k]));
  }
  __syncthreads();

  if (tid < 64) {
    const int lane = tid;
    float av[4]; int ai[4];
#pragma unroll
    for (int q = 0; q < 4; q++) { av[q] = FBIG; ai[q] = IBIG; }
#pragma unroll
    for (int q = 0; q < 4; q++) {
      int idx = lane + 64 * q;
      if (idx < 16 * KSEL) {
        float2 p = sml[idx];
        float cv = p.x; int ci = __float_as_int(p.y);
#pragma unroll
        for (int r = 0; r < 4; r++) {
          bool less = (cv < av[r]) || (cv == av[r] && ci < ai[r]);
          float nv = less ? cv : av[r];  int ni = less ? ci : ai[r];
          float xv = less ? av[r] : cv;  int xi = less ? ai[r] : ci;
          av[r] = nv; ai[r] = ni; cv = xv; ci = xi;
        }
      }
    }
#pragma unroll 1
    for (int k = 0; k < KSEL; k++) {
      float bv = av[0]; int bi = ai[0]; int bl = lane;
#pragma unroll
      for (int m = 1; m < 64; m <<= 1) {
        float ov = __shfl_xor(bv, m);
        int   oi = __shfl_xor(bi, m);
        int   ol = __shfl_xor(bl, m);
        if (ov < bv || (ov == bv && (oi < bi || (oi == bi && ol < bl)))) {
          bv = ov; bi = oi; bl = ol;
        }
      }
      if (lane == bl) {                         // winner consumes its head
        av[0] = av[1]; ai[0] = ai[1];
        av[1] = av[2]; ai[1] = ai[2];
        av[2] = av[3]; ai[2] = ai[3];
        av[3] = FBIG;  ai[3] = IBIG;
      }
      if (lane == 0)
        bcand[blockIdx.x * KSEL + k] = make_float2(bv, __int_as_float(bi));
    }
  }
}

// ---------------------------------------------------------------------------
// Kernel 2: exact global top-15 over 30720 block candidates (0.25MB), then
// label gather + vote. Strict > in argmax -> ties go to the smallest class,
// matching jnp.argmax. Single wave; all register arrays statically indexed.
// ---------------------------------------------------------------------------
__global__ __launch_bounds__(64) void k_final(const float2* __restrict__ bcand,
                                              const int* __restrict__ labels,
                                              float* __restrict__ out) {
  const int lane = threadIdx.x;
  float lv[KSEL]; int li[KSEL];
#pragma unroll
  for (int k = 0; k < KSEL; k++) { lv[k] = FBIG; li[k] = IBIG; }

  for (int c = lane; c < NCAND; c += 64) {     // 480 pairs per lane
    float2 p = bcand[c];
    float cv = p.x; int ci = __float_as_int(p.y);
    if (cv < lv[KSEL - 1] || (cv == lv[KSEL - 1] && ci < li[KSEL - 1])) {
#pragma unroll
      for (int q = 0; q < KSEL; q++) {
        bool less = (cv < lv[q]) || (cv == lv[q] && ci < li[q]);
        float nv = less ? cv : lv[q];  int ni = less ? ci : li[q];
        float xv = less ? lv[q] : cv;  int xi = less ? li[q] : ci;
        lv[q] = nv; li[q] = ni; cv = xv; ci = xi;
      }
    }
  }

  int c0 = 0, c1 = 0, c2 = 0;
#pragma unroll 1
  for (int k = 0; k < KSEL; k++) {
    float bv = lv[0]; int bi = li[0]; int bl = lane;
#pragma unroll
    for (int m = 1; m < 64; m <<= 1) {
      float ov = __shfl_xor(bv, m);
      int   oi = __shfl_xor(bi, m);
      int   ol = __shfl_xor(bl, m);
      if (ov < bv || (ov == bv && (oi < bi || (oi == bi && ol < bl)))) {
        bv = ov; bi = oi; bl = ol;
      }
    }
    if (lane == bl) {                           // winner consumes its head
#pragma unroll
      for (int q = 0; q < KSEL - 1; q++) { lv[q] = lv[q + 1]; li[q] = li[q + 1]; }
      lv[KSEL - 1] = FBIG; li[KSEL - 1] = IBIG;
    }
    if (lane == 0 && bi >= 0 && bi < N_PTS) {
      int lb = labels[bi];
      if (lb == 0) c0++; else if (lb == 1) c1++; else c2++;
    }
  }
  if (lane == 0) {
    int best = 0, bc = c0;
    if (c1 > bc) { best = 1; bc = c1; }
    if (c2 > bc) { best = 2; }
    out[0] = (float)best;
  }
}

extern "C" void kernel_launch(void* const* d_in, const int* in_sizes, int n_in,
                              void* d_out, int out_size, void* d_ws, size_t ws_size,
                              hipStream_t stream) {
  const float* x      = (const float*)d_in[0];
  const float* td     = (const float*)d_in[1];
  const int*   labels = (const int*)d_in[2];
  float*       out    = (float*)d_out;

  float2* bcand = (float2*)d_ws;               // NCAND float2 = 245,760 B

  k_dist <<<NBLK, TPB, 0, stream>>>(x, td, bcand);
  k_final<<<1,    64,  0, stream>>>(bcand, labels, out);
}

// Round 6
// 233.394 us; speedup vs baseline: 3.0840x; 3.0840x over previous
//
#include <hip/hip_runtime.h>

#define N_PTS   2000000
#define DIM     128
#define KSEL    15
#define TPB     256
#define NBLK    2048
#define NCL     (NBLK * (TPB / 4))       // 131072 4-lane clusters, sweep stride
#define NBLK3   2048
#define CAP     32768
#define FBIG    3.4028235e38f
#define IBIG    0x7fffffff

// ---------------------------------------------------------------------------
// Kernel 1: distances. 4 lanes per row: each lane owns a 32-element slice
// (8 x float4, strided so each load instr is 64B-line coalesced across the
// wave). Two independent fma chains (t.t and t.x), one combine, 2-shfl
// reduce. ~0.64 instr/B vs 0.88 in the 16-lane version — targets the
// instruction-issue margin that capped read BW at ~4.7 TB/s.
// Grid-stride sweep keeps all clusters in one contiguous window.
// ---------------------------------------------------------------------------
__global__ __launch_bounds__(TPB) void k_dist(const float* __restrict__ x,
                                              const float* __restrict__ td,
                                              float* __restrict__ d2out,
                                              float* __restrict__ bmin) {
  const int tid = threadIdx.x;
  const int c   = tid & 3;                          // lane within cluster
  const int cl  = blockIdx.x * (TPB / 4) + (tid >> 2);

  const float4* x4 = (const float4*)x;
  float4 xv[8];
#pragma unroll
  for (int j = 0; j < 8; j++) xv[j] = x4[j * 4 + c];

  float xsq = 0.f;
#pragma unroll
  for (int j = 0; j < 8; j++)
    xsq += xv[j].x * xv[j].x + xv[j].y * xv[j].y
         + xv[j].z * xv[j].z + xv[j].w * xv[j].w;
  xsq += __shfl_xor(xsq, 1);
  xsq += __shfl_xor(xsq, 2);

  float mymin = FBIG;
#pragma unroll 2
  for (int row = cl; row < N_PTS; row += NCL) {
    const float4* rp = (const float4*)(td + (size_t)row * DIM);
    float4 tv[8];
#pragma unroll
    for (int j = 0; j < 8; j++) tv[j] = rp[j * 4 + c];

    float att = 0.f, atx = 0.f;
#pragma unroll
    for (int j = 0; j < 8; j++) {
      att = fmaf(tv[j].x, tv[j].x, att);  atx = fmaf(tv[j].x, xv[j].x, atx);
      att = fmaf(tv[j].y, tv[j].y, att);  atx = fmaf(tv[j].y, xv[j].y, atx);
      att = fmaf(tv[j].z, tv[j].z, att);  atx = fmaf(tv[j].z, xv[j].z, atx);
      att = fmaf(tv[j].w, tv[j].w, att);  atx = fmaf(tv[j].w, xv[j].w, atx);
    }
    float s = fmaf(-2.f, atx, att);
    s += __shfl_xor(s, 1);
    s += __shfl_xor(s, 2);
    float d2 = fmaxf(s + xsq, 0.f);
    if (c == 0) d2out[row] = d2;
    mymin = fminf(mymin, d2);
  }

  __shared__ float smin[TPB];
  smin[tid] = mymin;
  __syncthreads();
  for (int s = TPB / 2; s > 0; s >>= 1) {
    if (tid < s) smin[tid] = fminf(smin[tid], smin[tid + s]);
    __syncthreads();
  }
  if (tid == 0) bmin[blockIdx.x] = smin[0];
}

// ---------------------------------------------------------------------------
// Kernel 2: T = 15th-smallest block-min. Single wave, static indexing only.
// Each block-min is a real point's d2, so count(d2<=T) >= 15 is guaranteed,
// and the true 15th-smallest distance <= T.
// ---------------------------------------------------------------------------
__global__ __launch_bounds__(64) void k_thresh(const float* __restrict__ bmin,
                                               float* __restrict__ thr,
                                               int* __restrict__ cnt) {
  const int lane = threadIdx.x;
  float lv[KSEL];
#pragma unroll
  for (int k = 0; k < KSEL; k++) lv[k] = FBIG;

  for (int i = lane; i < NBLK; i += 64) {          // 32 values per lane
    float v = bmin[i];
#pragma unroll
    for (int q = 0; q < KSEL; q++) {               // static bubble insert
      float mn = fminf(lv[q], v);
      v = fmaxf(lv[q], v);
      lv[q] = mn;
    }
  }

  float T = FBIG;
#pragma unroll 1
  for (int k = 0; k < KSEL; k++) {
    float bv = lv[0];
    int   bl = lane;
#pragma unroll
    for (int m = 1; m < 64; m <<= 1) {
      float ov = __shfl_xor(bv, m);
      int   ol = __shfl_xor(bl, m);
      if (ov < bv || (ov == bv && ol < bl)) { bv = ov; bl = ol; }
    }
    if (lane == bl) {                               // winner consumes head
#pragma unroll
      for (int q = 0; q < KSEL - 1; q++) lv[q] = lv[q + 1];
      lv[KSEL - 1] = FBIG;
    }
    T = bv;
  }
  if (lane == 0) { thr[0] = T; cnt[0] = 0; }
}

// ---------------------------------------------------------------------------
// Kernel 3: compact indices with d2 <= T.
// ---------------------------------------------------------------------------
__global__ __launch_bounds__(TPB) void k_compact(const float* __restrict__ d2,
                                                 const float* __restrict__ thr,
                                                 int* __restrict__ cnt,
                                                 int* __restrict__ cand) {
  const float T = thr[0];
  int i = blockIdx.x * TPB + threadIdx.x;
  const int stride = gridDim.x * TPB;
  for (; i < N_PTS; i += stride) {
    if (d2[i] <= T) {
      int p = atomicAdd(cnt, 1);
      if (p < CAP) cand[p] = i;
    }
  }
}

// ---------------------------------------------------------------------------
// Kernel 4: exact top-15 over candidates ordered by (d2, index) — lowest
// index wins ties, matching lax.top_k. Vote with strict >, ties to the
// smallest class (matching jnp.argmax). All static indexing.
// ---------------------------------------------------------------------------
__global__ __launch_bounds__(64) void k_final(const float* __restrict__ d2,
                                              const int* __restrict__ cnt,
                                              const int* __restrict__ cand,
                                              const int* __restrict__ labels,
                                              float* __restrict__ out) {
  const int lane = threadIdx.x;
  int n = cnt[0];
  if (n > CAP) n = CAP;

  float lv[KSEL]; int li[KSEL];
#pragma unroll
  for (int k = 0; k < KSEL; k++) { lv[k] = FBIG; li[k] = IBIG; }

  for (int cdx = lane; cdx < n; cdx += 64) {
    int vi = cand[cdx];
    float v = d2[vi];
#pragma unroll
    for (int q = 0; q < KSEL; q++) {               // static pair bubble insert
      bool less = (v < lv[q]) || (v == lv[q] && vi < li[q]);
      float tv = less ? lv[q] : v;  int ti = less ? li[q] : vi;
      float nv = less ? v : lv[q];  int ni = less ? vi : li[q];
      lv[q] = nv; li[q] = ni;
      v = tv; vi = ti;
    }
  }

  int c0 = 0, c1 = 0, c2 = 0;
#pragma unroll 1
  for (int k = 0; k < KSEL; k++) {
    float bv = lv[0]; int bi = li[0]; int bl = lane;
#pragma unroll
    for (int m = 1; m < 64; m <<= 1) {
      float ov = __shfl_xor(bv, m);
      int   oi = __shfl_xor(bi, m);
      int   ol = __shfl_xor(bl, m);
      if (ov < bv || (ov == bv && (oi < bi || (oi == bi && ol < bl)))) {
        bv = ov; bi = oi; bl = ol;
      }
    }
    if (lane == bl) {                               // winner consumes head
#pragma unroll
      for (int q = 0; q < KSEL - 1; q++) { lv[q] = lv[q + 1]; li[q] = li[q + 1]; }
      lv[KSEL - 1] = FBIG; li[KSEL - 1] = IBIG;
    }
    if (lane == 0 && bi >= 0 && bi < N_PTS) {
      int lb = labels[bi];
      if (lb == 0) c0++; else if (lb == 1) c1++; else c2++;
    }
  }
  if (lane == 0) {
    int best = 0, bc = c0;
    if (c1 > bc) { best = 1; bc = c1; }
    if (c2 > bc) { best = 2; }
    out[0] = (float)best;
  }
}

extern "C" void kernel_launch(void* const* d_in, const int* in_sizes, int n_in,
                              void* d_out, int out_size, void* d_ws, size_t ws_size,
                              hipStream_t stream) {
  const float* x      = (const float*)d_in[0];
  const float* td     = (const float*)d_in[1];
  const int*   labels = (const int*)d_in[2];
  float*       out    = (float*)d_out;

  char* w = (char*)d_ws;
  float* d2   = (float*)w;                                   // N_PTS floats
  float* bmin = (float*)(w + (size_t)N_PTS * sizeof(float)); // NBLK floats
  float* thr  = bmin + NBLK;                                 // 1 float
  int*   cnt  = (int*)(thr + 1);                             // 1 int
  int*   cand = cnt + 1;                                     // CAP ints

  k_dist   <<<NBLK, TPB, 0, stream>>>(x, td, d2, bmin);
  k_thresh <<<1,    64,  0, stream>>>(bmin, thr, cnt);
  k_compact<<<NBLK3, TPB, 0, stream>>>(d2, thr, cnt, cand);
  k_final  <<<1,    64,  0, stream>>>(d2, cnt, cand, labels, out);
}